// Round 6
// baseline (222.390 us; speedup 1.0000x reference)
//
#include <hip/hip_runtime.h>

#define BATCH    1024
#define NUM_VARS 2048
#define LEAVES   (2 * NUM_VARS)              // 4096
#define LEVELS   12
#define WIDTH    4096

typedef float vfloat4 __attribute__((ext_vector_type(4)));  // native vec for nt-store

// ---------------------------------------------------------------------------
// Transpose x[1024][2048] -> xT[2048][1024] (8 MB). Leaves stay implicit:
//   value(c) = xT[c][b]                for c < NUM_VARS
//   value(c) = 1 - xT[c-NUM_VARS][b]   for NUM_VARS <= c < LEAVES
// xT uses NORMAL stores: it is re-read ~51k rows' worth across all levels.
// ---------------------------------------------------------------------------
__global__ __launch_bounds__(1024) void transpose_kernel(const float* __restrict__ x,
                                                         float* __restrict__ xT)
{
    __shared__ float tile[64][65];
    const int v0 = blockIdx.x * 64;           // 32 v-tiles
    const int bb = blockIdx.y * 64;           // 16 b-tiles
    const int tv = threadIdx.x;               // 0..63
    const int tb = threadIdx.y;               // 0..15
    #pragma unroll
    for (int i = 0; i < 4; ++i) {
        const int bl = tb + i * 16;
        tile[tv][bl] = x[(size_t)(bb + bl) * NUM_VARS + v0 + tv];   // coalesced in tv
    }
    __syncthreads();
    const int wb = threadIdx.x;
    #pragma unroll
    for (int i = 0; i < 4; ++i) {
        const int vl = tb + i * 16;
        xT[(size_t)(v0 + vl) * BATCH + bb + wb] = tile[vl][wb];      // coalesced in wb
    }
}

// Branch-free (uniform) child row pointer: leaves fold to xT via c & 2047,
// internal nodes to buf. The 1-x fixup is applied after the load so all
// loads issue unconditionally (deep VMEM pipeline).
__device__ __forceinline__ const float4* child_ptr(const float* __restrict__ xT,
                                                   const float* __restrict__ buf,
                                                   int c)
{
    const float* p = (c < LEAVES)
        ? xT  + (size_t)(c & (NUM_VARS - 1)) * BATCH
        : buf + (size_t)(c - LEAVES) * BATCH;
    return (const float4*)p;
}

__device__ __forceinline__ float4 fixup(float4 v, int c)
{
    if (c >= NUM_VARS && c < LEAVES) {        // uniform; complement literal
        v.x = 1.0f - v.x; v.y = 1.0f - v.y; v.z = 1.0f - v.z; v.w = 1.0f - v.w;
    }
    return v;
}

__device__ __forceinline__ float4 combine(float4 a0, float4 a1, float4 a2, float4 a3, int o)
{
    float4 r;
    if (o == 0) {   // AND: left-to-right product (np.prod order)
        r.x = ((a0.x * a1.x) * a2.x) * a3.x;
        r.y = ((a0.y * a1.y) * a2.y) * a3.y;
        r.z = ((a0.z * a1.z) * a2.z) * a3.z;
        r.w = ((a0.w * a1.w) * a2.w) * a3.w;
    } else {        // OR: left-to-right sum
        r.x = ((a0.x + a1.x) + a2.x) + a3.x;
        r.y = ((a0.y + a1.y) + a2.y) + a3.y;
        r.z = ((a0.z + a1.z) + a2.z) + a3.z;
        r.w = ((a0.w + a1.w) + a2.w) + a3.w;
    }
    return r;
}

__device__ __forceinline__ void nt_store4(float* base, int t, float4 r)
{
    vfloat4 v = {r.x, r.y, r.z, r.w};
    __builtin_nontemporal_store(v, (vfloat4*)base + t);
}

// ---------------------------------------------------------------------------
// One level, full batch. 2 nodes per 256-thread block; thread t owns float4
// column t for BOTH nodes -> 8 independent coalesced loads in flight.
// buf writes are NON-TEMPORAL: full-line streaming stores, no L2 allocate /
// no RFO (experiment: distinguishes store-RFO vs L2-hit vs fabric-bound).
// ---------------------------------------------------------------------------
__global__ __launch_bounds__(256) void level_kernel(const float* __restrict__ xT,
                                                    const float* __restrict__ buf,
                                                    float* __restrict__ out_base,
                                                    const int4* __restrict__ child,
                                                    const int*  __restrict__ op,
                                                    float* __restrict__ root_out)
{
    const int t  = threadIdx.x;               // float4 index into 1024-wide row
    const int w0 = blockIdx.x * 2;
    const int w1 = w0 + 1;

    const int4 c0 = child[w0];                // wave-uniform -> scalar loads
    const int4 c1 = child[w1];
    const int  o0 = op[w0];
    const int  o1 = op[w1];

    // Issue all 8 loads unconditionally.
    float4 a0 = child_ptr(xT, buf, c0.x)[t];
    float4 a1 = child_ptr(xT, buf, c0.y)[t];
    float4 a2 = child_ptr(xT, buf, c0.z)[t];
    float4 a3 = child_ptr(xT, buf, c0.w)[t];
    float4 b0 = child_ptr(xT, buf, c1.x)[t];
    float4 b1 = child_ptr(xT, buf, c1.y)[t];
    float4 b2 = child_ptr(xT, buf, c1.z)[t];
    float4 b3 = child_ptr(xT, buf, c1.w)[t];

    a0 = fixup(a0, c0.x); a1 = fixup(a1, c0.y); a2 = fixup(a2, c0.z); a3 = fixup(a3, c0.w);
    b0 = fixup(b0, c1.x); b1 = fixup(b1, c1.y); b2 = fixup(b2, c1.z); b3 = fixup(b3, c1.w);

    const float4 r0 = combine(a0, a1, a2, a3, o0);
    const float4 r1 = combine(b0, b1, b2, b3, o1);

    nt_store4(out_base + (size_t)w0 * BATCH, t, r0);
    nt_store4(out_base + (size_t)w1 * BATCH, t, r1);

    if (root_out != nullptr && w1 == WIDTH - 1) {
        ((float4*)root_out)[t] = r1;          // root row -> d_out (folded copy)
    }
}

extern "C" void kernel_launch(void* const* d_in, const int* in_sizes, int n_in,
                              void* d_out, int out_size, void* d_ws, size_t ws_size,
                              hipStream_t stream)
{
    const float* x       = (const float*)d_in[0];
    const int4*  child4  = (const int4*)d_in[1];
    const int*   op_type = (const int*)d_in[2];
    float*       out     = (float*)d_out;

    // ws layout: [xT: 2048*1024 f32 = 8 MB][buf: 49152 rows * 4 KB = 192 MB]
    float* xT  = (float*)d_ws;
    float* buf = xT + (size_t)NUM_VARS * BATCH;

    {
        dim3 blk(64, 16);
        dim3 grd(NUM_VARS / 64, BATCH / 64);
        transpose_kernel<<<grd, blk, 0, stream>>>(x, xT);
    }

    for (int l = 0; l < LEVELS; ++l) {
        const int4* child = child4 + (size_t)l * WIDTH;
        const int*  op    = op_type + (size_t)l * WIDTH;
        float* out_base   = buf + (size_t)l * WIDTH * BATCH;
        float* root_out   = (l == LEVELS - 1) ? out : nullptr;
        level_kernel<<<WIDTH / 2, 256, 0, stream>>>(xT, buf, out_base,
                                                    child, op, root_out);
    }
}

// Round 7
// 176.433 us; speedup vs baseline: 1.2605x; 1.2605x over previous
//
#include <hip/hip_runtime.h>

#define BATCH    1024
#define NUM_VARS 2048
#define LEAVES   (2 * NUM_VARS)              // 4096
#define LEVELS   12
#define WIDTH    4096
#define FP16_LVLS 3                           // levels 0..2 stored fp16 (proven-safe range)
#define FP16_END (LEAVES + FP16_LVLS * WIDTH) // node idx < FP16_END -> fp16 storage

typedef _Float16 half4v __attribute__((ext_vector_type(4)));

// ws layout:
//   hbuf: 2048 leaf rows + 12288 level-0..2 rows, 1024 halves each  (28 MB)
//   fbuf: 9*4096 level-3..11 rows, 1024 floats each                (144 MB)
// hbuf row index for child c: c<2048 -> c ; else c-2048 (leaves fold via 1-x fixup).

// ---------------------------------------------------------------------------
// Transpose x[1024][2048] -> fp16 rows hbuf[v][b], v in [0,2048).
// ---------------------------------------------------------------------------
__global__ __launch_bounds__(1024) void transpose_kernel(const float* __restrict__ x,
                                                         _Float16* __restrict__ hbuf)
{
    __shared__ float tile[64][65];
    const int v0 = blockIdx.x * 64;           // 32 v-tiles
    const int bb = blockIdx.y * 64;           // 16 b-tiles
    const int tv = threadIdx.x;               // 0..63
    const int tb = threadIdx.y;               // 0..15
    #pragma unroll
    for (int i = 0; i < 4; ++i) {
        const int bl = tb + i * 16;
        tile[tv][bl] = x[(size_t)(bb + bl) * NUM_VARS + v0 + tv];   // coalesced in tv
    }
    __syncthreads();
    const int wb = threadIdx.x;
    #pragma unroll
    for (int i = 0; i < 4; ++i) {
        const int vl = tb + i * 16;
        hbuf[(size_t)(v0 + vl) * BATCH + bb + wb] = (_Float16)tile[vl][wb];
    }
}

// ---------------------------------------------------------------------------
// Load one child's float4 batch-column. Region select is wave-uniform.
// ---------------------------------------------------------------------------
__device__ __forceinline__ float4 load_child(const _Float16* __restrict__ hbuf,
                                             const float* __restrict__ fbuf,
                                             int c, int t)
{
    if (c < FP16_END) {
        const int row = (c < NUM_VARS) ? c : c - NUM_VARS * 1 - ((c < LEAVES) ? 0 : NUM_VARS) + ((c < LEAVES) ? 0 : NUM_VARS);
        // simplified: leaves [0,2048) -> row c; complement leaves [2048,4096) -> row c-2048;
        // internal [4096,16384) -> row c-2048.
        const int r = (c < NUM_VARS) ? c : (c - NUM_VARS - ((c >= LEAVES) ? 0 : 0));
        (void)row; (void)r;
        const int rr = (c < NUM_VARS) ? c : c - NUM_VARS;          // works for both: see note
        const int rowi = (c >= LEAVES) ? (c - NUM_VARS) : rr;      // c-2048 for c>=4096 too
        half4v h = ((const half4v*)(hbuf + (size_t)rowi * BATCH))[t];
        float4 v = make_float4((float)h.x, (float)h.y, (float)h.z, (float)h.w);
        if (c >= NUM_VARS && c < LEAVES) {    // complement leaf, uniform
            v.x = 1.0f - v.x; v.y = 1.0f - v.y; v.z = 1.0f - v.z; v.w = 1.0f - v.w;
        }
        return v;
    } else {
        return ((const float4*)(fbuf + (size_t)(c - FP16_END) * BATCH))[t];
    }
}

__device__ __forceinline__ float4 combine(float4 a0, float4 a1, float4 a2, float4 a3, int o)
{
    float4 r;
    if (o == 0) {   // AND: left-to-right product (np.prod order)
        r.x = ((a0.x * a1.x) * a2.x) * a3.x;
        r.y = ((a0.y * a1.y) * a2.y) * a3.y;
        r.z = ((a0.z * a1.z) * a2.z) * a3.z;
        r.w = ((a0.w * a1.w) * a2.w) * a3.w;
    } else {        // OR: left-to-right sum
        r.x = ((a0.x + a1.x) + a2.x) + a3.x;
        r.y = ((a0.y + a1.y) + a2.y) + a3.y;
        r.z = ((a0.z + a1.z) + a2.z) + a3.z;
        r.w = ((a0.w + a1.w) + a2.w) + a3.w;
    }
    return r;
}

// ---------------------------------------------------------------------------
// One level, full batch. 2 nodes per 256-thread block. Compute always fp32;
// output rows go to hout (fp16, levels 0..2) or fout (fp32, levels 3..11).
// ---------------------------------------------------------------------------
__global__ __launch_bounds__(256) void level_kernel(const _Float16* __restrict__ hbuf,
                                                    const float* __restrict__ fbuf,
                                                    _Float16* __restrict__ hout,
                                                    float* __restrict__ fout,
                                                    const int4* __restrict__ child,
                                                    const int*  __restrict__ op,
                                                    float* __restrict__ root_out)
{
    const int t  = threadIdx.x;               // float4 index into 1024-wide row
    const int w0 = blockIdx.x * 2;
    const int w1 = w0 + 1;

    const int4 c0 = child[w0];                // wave-uniform -> scalar loads
    const int4 c1 = child[w1];
    const int  o0 = op[w0];
    const int  o1 = op[w1];

    const float4 a0 = load_child(hbuf, fbuf, c0.x, t);
    const float4 a1 = load_child(hbuf, fbuf, c0.y, t);
    const float4 a2 = load_child(hbuf, fbuf, c0.z, t);
    const float4 a3 = load_child(hbuf, fbuf, c0.w, t);
    const float4 b0 = load_child(hbuf, fbuf, c1.x, t);
    const float4 b1 = load_child(hbuf, fbuf, c1.y, t);
    const float4 b2 = load_child(hbuf, fbuf, c1.z, t);
    const float4 b3 = load_child(hbuf, fbuf, c1.w, t);

    const float4 r0 = combine(a0, a1, a2, a3, o0);
    const float4 r1 = combine(b0, b1, b2, b3, o1);

    if (hout != nullptr) {                    // fp16 level (0..2)
        half4v h0 = {(_Float16)r0.x, (_Float16)r0.y, (_Float16)r0.z, (_Float16)r0.w};
        half4v h1 = {(_Float16)r1.x, (_Float16)r1.y, (_Float16)r1.z, (_Float16)r1.w};
        ((half4v*)(hout + (size_t)w0 * BATCH))[t] = h0;
        ((half4v*)(hout + (size_t)w1 * BATCH))[t] = h1;
    } else {                                  // fp32 level (3..11)
        ((float4*)(fout + (size_t)w0 * BATCH))[t] = r0;
        ((float4*)(fout + (size_t)w1 * BATCH))[t] = r1;
    }

    if (root_out != nullptr && w1 == WIDTH - 1) {
        ((float4*)root_out)[t] = r1;          // root row -> d_out (folded copy)
    }
}

extern "C" void kernel_launch(void* const* d_in, const int* in_sizes, int n_in,
                              void* d_out, int out_size, void* d_ws, size_t ws_size,
                              hipStream_t stream)
{
    const float* x       = (const float*)d_in[0];
    const int4*  child4  = (const int4*)d_in[1];
    const int*   op_type = (const int*)d_in[2];
    float*       out     = (float*)d_out;

    _Float16* hbuf = (_Float16*)d_ws;                                   // 28 MB
    float*    fbuf = (float*)((char*)d_ws + (size_t)(NUM_VARS + FP16_LVLS * WIDTH)
                                            * BATCH * sizeof(_Float16)); // 144 MB

    {
        dim3 blk(64, 16);
        dim3 grd(NUM_VARS / 64, BATCH / 64);
        transpose_kernel<<<grd, blk, 0, stream>>>(x, hbuf);
    }

    for (int l = 0; l < LEVELS; ++l) {
        const int4* child = child4 + (size_t)l * WIDTH;
        const int*  op    = op_type + (size_t)l * WIDTH;
        _Float16* hout = nullptr;
        float*    fout = nullptr;
        if (l < FP16_LVLS) {
            hout = hbuf + (size_t)(NUM_VARS + l * WIDTH) * BATCH;
        } else {
            fout = fbuf + (size_t)(l - FP16_LVLS) * WIDTH * BATCH;
        }
        float* root_out = (l == LEVELS - 1) ? out : nullptr;
        level_kernel<<<WIDTH / 2, 256, 0, stream>>>(hbuf, fbuf, hout, fout,
                                                    child, op, root_out);
    }
}

// Round 8
// 110.910 us; speedup vs baseline: 2.0051x; 1.5908x over previous
//
#include <hip/hip_runtime.h>

#define BATCH    1024
#define NUM_VARS 2048
#define LEAVES   (2 * NUM_VARS)              // 4096
#define LEVELS   12
#define WIDTH    4096
#define TOTAL    (LEAVES + LEVELS * WIDTH)   // 53248

// ws layout: [xT: 8 MB][buf: 12*4096 rows * 4 KB = 192 MB][flags: TOTAL bytes]

// ---------------------------------------------------------------------------
// Transpose x[1024][2048] -> xT[2048][1024]. Leaves implicit:
//   value(c) = xT[c][b] (c<NV), 1 - xT[c-NV][b] (NV<=c<LEAVES).
// ---------------------------------------------------------------------------
__global__ __launch_bounds__(1024) void transpose_kernel(const float* __restrict__ x,
                                                         float* __restrict__ xT)
{
    __shared__ float tile[64][65];
    const int v0 = blockIdx.x * 64;
    const int bb = blockIdx.y * 64;
    const int tv = threadIdx.x;               // 0..63
    const int tb = threadIdx.y;               // 0..15
    #pragma unroll
    for (int i = 0; i < 4; ++i) {
        const int bl = tb + i * 16;
        tile[tv][bl] = x[(size_t)(bb + bl) * NUM_VARS + v0 + tv];   // coalesced in tv
    }
    __syncthreads();
    const int wb = threadIdx.x;
    #pragma unroll
    for (int i = 0; i < 4; ++i) {
        const int vl = tb + i * 16;
        xT[(size_t)(v0 + vl) * BATCH + bb + wb] = tile[vl][wb];      // coalesced in wb
    }
}

// ---------------------------------------------------------------------------
// Backward reachability marking, single block (1024 threads).
// Phase 0: zero flags. Then mark root, then for l=11..0 mark children of
// marked level-l nodes. All marks target strictly lower node ids, so
// __syncthreads between levels gives the needed ordering (block-local
// global-memory visibility is guaranteed across __syncthreads).
// ---------------------------------------------------------------------------
__global__ __launch_bounds__(1024) void mark_kernel(const int4* __restrict__ child4,
                                                    unsigned char* __restrict__ flags)
{
    const int tid = threadIdx.x;

    // zero all flags (TOTAL = 53248 bytes = 13312 words)
    for (int i = tid; i < TOTAL / 4; i += 1024) ((unsigned int*)flags)[i] = 0u;
    __syncthreads();
    if (tid == 0) flags[TOTAL - 1] = 1;       // root
    __syncthreads();

    for (int l = LEVELS - 1; l >= 0; --l) {
        const int base = LEAVES + l * WIDTH;  // level-l node ids [base, base+4096)
        const unsigned int f = *(const unsigned int*)(flags + base + (tid << 2));
        if (f != 0u) {
            #pragma unroll
            for (int j = 0; j < 4; ++j) {
                if ((f >> (8 * j)) & 0xFFu) {
                    const int w = (tid << 2) + j;
                    const int4 c = child4[l * WIDTH + w];
                    flags[c.x] = 1; flags[c.y] = 1; flags[c.z] = 1; flags[c.w] = 1;
                }
            }
        }
        __syncthreads();
    }
}

// Branch-free (uniform) child row pointer: leaves fold to xT, internal to buf.
__device__ __forceinline__ const float4* child_ptr(const float* __restrict__ xT,
                                                   const float* __restrict__ buf,
                                                   int c)
{
    const float* p = (c < LEAVES)
        ? xT  + (size_t)(c & (NUM_VARS - 1)) * BATCH
        : buf + (size_t)(c - LEAVES) * BATCH;
    return (const float4*)p;
}

__device__ __forceinline__ float4 fixup(float4 v, int c)
{
    if (c >= NUM_VARS && c < LEAVES) {        // complement leaf, wave-uniform
        v.x = 1.0f - v.x; v.y = 1.0f - v.y; v.z = 1.0f - v.z; v.w = 1.0f - v.w;
    }
    return v;
}

// ---------------------------------------------------------------------------
// One level. One node per block; blocks for unneeded nodes exit on one
// flag byte. Thread t owns float4 batch-column t (256 x 4 = 1024).
// Last level: only the root (w = WIDTH-1) is flagged; it writes d_out.
// ---------------------------------------------------------------------------
__global__ __launch_bounds__(256) void level_kernel(const float* __restrict__ xT,
                                                    const float* __restrict__ buf,
                                                    float* __restrict__ out_base,
                                                    const int4* __restrict__ child,
                                                    const int*  __restrict__ op,
                                                    const unsigned char* __restrict__ flags,
                                                    int node_base,
                                                    int is_last,
                                                    float* __restrict__ root_out)
{
    const int w = blockIdx.x;
    if (flags[node_base + w] == 0) return;    // 4095/4096 blocks leave here

    const int t = threadIdx.x;
    const int4 c = child[w];                  // wave-uniform -> scalar loads
    const int  o = op[w];

    float4 a0 = child_ptr(xT, buf, c.x)[t];
    float4 a1 = child_ptr(xT, buf, c.y)[t];
    float4 a2 = child_ptr(xT, buf, c.z)[t];
    float4 a3 = child_ptr(xT, buf, c.w)[t];
    a0 = fixup(a0, c.x); a1 = fixup(a1, c.y); a2 = fixup(a2, c.z); a3 = fixup(a3, c.w);

    float4 r;
    if (o == 0) {   // AND: left-to-right product (np.prod order)
        r.x = ((a0.x * a1.x) * a2.x) * a3.x;
        r.y = ((a0.y * a1.y) * a2.y) * a3.y;
        r.z = ((a0.z * a1.z) * a2.z) * a3.z;
        r.w = ((a0.w * a1.w) * a2.w) * a3.w;
    } else {        // OR: left-to-right sum
        r.x = ((a0.x + a1.x) + a2.x) + a3.x;
        r.y = ((a0.y + a1.y) + a2.y) + a3.y;
        r.z = ((a0.z + a1.z) + a2.z) + a3.z;
        r.w = ((a0.w + a1.w) + a2.w) + a3.w;
    }

    if (is_last) {
        if (w == WIDTH - 1) ((float4*)root_out)[t] = r;   // root row -> d_out
    } else {
        ((float4*)(out_base + (size_t)w * BATCH))[t] = r;
    }
}

extern "C" void kernel_launch(void* const* d_in, const int* in_sizes, int n_in,
                              void* d_out, int out_size, void* d_ws, size_t ws_size,
                              hipStream_t stream)
{
    const float* x       = (const float*)d_in[0];
    const int4*  child4  = (const int4*)d_in[1];
    const int*   op_type = (const int*)d_in[2];
    float*       out     = (float*)d_out;

    float* xT  = (float*)d_ws;                                   // 8 MB
    float* buf = xT + (size_t)NUM_VARS * BATCH;                  // 192 MB
    unsigned char* flags = (unsigned char*)(buf + (size_t)LEVELS * WIDTH * BATCH);

    {
        dim3 blk(64, 16);
        dim3 grd(NUM_VARS / 64, BATCH / 64);
        transpose_kernel<<<grd, blk, 0, stream>>>(x, xT);
    }

    mark_kernel<<<1, 1024, 0, stream>>>(child4, flags);

    for (int l = 0; l < LEVELS; ++l) {
        const int4* child = child4 + (size_t)l * WIDTH;
        const int*  op    = op_type + (size_t)l * WIDTH;
        float* out_base   = buf + (size_t)l * WIDTH * BATCH;
        const int is_last = (l == LEVELS - 1) ? 1 : 0;
        level_kernel<<<WIDTH, 256, 0, stream>>>(xT, buf, out_base, child, op,
                                                flags, LEAVES + l * WIDTH,
                                                is_last, out);
    }
}